// Round 3
// baseline (160.037 us; speedup 1.0000x reference)
//
#include <hip/hip_runtime.h>
#include <math.h>

#define NB    8
#define NN    100
#define NPRED (NB*NN)     // 800
#define MT    20
#define NT    (NB*MT)     // 160
#define HW    25600
#define NCLS  80

typedef float  f32x4  __attribute__((ext_vector_type(4)));
typedef short  short8 __attribute__((ext_vector_type(8)));
typedef unsigned short u16x8 __attribute__((ext_vector_type(8)));

// truncated-hi split: hi = trunc16(f)  (|lo| <= 2^-8 |f|, residual after RNE(lo) ~ 2^-17)
static __device__ __forceinline__ unsigned short f2bf_rne(float f){
  unsigned u = __float_as_uint(f);
  return (unsigned short)((u + 0x7fffu + ((u >> 16) & 1u)) >> 16);
}

// ---------------- split-bf16 MFMA GEMM, BK=32, padded LDS, K-split, fused norms ----------------
// Block tile 64x160x32; 4 waves 2x2, wave tile 32x80 (2x5 frags of 16x16x32).
// LDS rows padded to 36 u16 (72B) -> all ds ops <=2-way bank aliasing (free).
#define LDP 36
__global__ __launch_bounds__(256, 4)
void gemm_split(const float* __restrict__ A, const float* __restrict__ Bm,
                float* __restrict__ part, float* __restrict__ pnp,
                float* __restrict__ tnp, int Kc, int ksteps){
  __shared__ unsigned short sAhi[64*LDP], sAlo[64*LDP];
  __shared__ unsigned short sBhi[160*LDP], sBlo[160*LDP];

  const int t     = threadIdx.x;
  const int mtile = blockIdx.x, ks = blockIdx.y;
  const int lane  = t & 63, w = t >> 6;
  const int wr = w >> 1, wc = w & 1;
  const int fr = lane & 15, fq = lane >> 4;
  const int kbase = ks * Kc;

  // staging assignment: 8 consecutive elems per (row, slot8)
  const int arow = t >> 2, asl = t & 3;           // A: 64 rows x 4 slots
  const int agrow = mtile * 64 + arow;
  const bool aok = (agrow < NPRED);

  f32x4 acc[2][5];
  #pragma unroll
  for (int r = 0; r < 2; r++)
    #pragma unroll
    for (int c = 0; c < 5; c++) acc[r][c] = (f32x4){0.f,0.f,0.f,0.f};

  float asum = 0.f;
  float bsum[3] = {0.f, 0.f, 0.f};

  for (int step = 0; step < ksteps; ++step){
    const int k0 = kbase + step * 32;
    // ---- stage A: 8 floats/thread ----
    {
      float v[8];
      if (aok){
        const float4* p = (const float4*)(A + (size_t)agrow * HW + k0 + asl * 8);
        float4 x0 = p[0], x1 = p[1];
        v[0]=x0.x; v[1]=x0.y; v[2]=x0.z; v[3]=x0.w;
        v[4]=x1.x; v[5]=x1.y; v[6]=x1.z; v[7]=x1.w;
      } else {
        #pragma unroll
        for (int i = 0; i < 8; i++) v[i] = 0.f;
      }
      u16x8 H, L;
      #pragma unroll
      for (int i = 0; i < 8; i++){
        asum += v[i] * v[i];
        unsigned u = __float_as_uint(v[i]);
        H[i] = (unsigned short)(u >> 16);
        float hif = __uint_as_float(u & 0xffff0000u);
        L[i] = f2bf_rne(v[i] - hif);
      }
      const int eo = arow * LDP + asl * 8;
      *(u16x8*)&sAhi[eo] = H;
      *(u16x8*)&sAlo[eo] = L;
    }
    // ---- stage B: 160 rows x 4 slots = 640 quads, 2.5 rounds ----
    #pragma unroll
    for (int r = 0; r < 3; ++r){
      const int q = t + r * 256;
      if (q < 640){
        const int row = q >> 2, sl = q & 3;
        const float4* p = (const float4*)(Bm + (size_t)row * HW + k0 + sl * 8);
        float4 x0 = p[0], x1 = p[1];
        float v[8];
        v[0]=x0.x; v[1]=x0.y; v[2]=x0.z; v[3]=x0.w;
        v[4]=x1.x; v[5]=x1.y; v[6]=x1.z; v[7]=x1.w;
        u16x8 H, L;
        #pragma unroll
        for (int i = 0; i < 8; i++){
          bsum[r] += v[i] * v[i];
          unsigned u = __float_as_uint(v[i]);
          H[i] = (unsigned short)(u >> 16);
          float hif = __uint_as_float(u & 0xffff0000u);
          L[i] = f2bf_rne(v[i] - hif);
        }
        const int eo = row * LDP + sl * 8;
        *(u16x8*)&sBhi[eo] = H;
        *(u16x8*)&sBlo[eo] = L;
      }
    }
    __syncthreads();
    // ---- MFMA: 2x5 frags x 3 precision terms (K=32 = whole BK) ----
    short8 ah[2], al[2];
    #pragma unroll
    for (int r = 0; r < 2; r++){
      const int eo = (wr * 32 + r * 16 + fr) * LDP + fq * 8;
      ah[r] = *(const short8*)&sAhi[eo];
      al[r] = *(const short8*)&sAlo[eo];
    }
    #pragma unroll
    for (int c = 0; c < 5; c++){
      const int eo = (wc * 80 + c * 16 + fr) * LDP + fq * 8;
      short8 bh = *(const short8*)&sBhi[eo];
      short8 bl = *(const short8*)&sBlo[eo];
      #pragma unroll
      for (int r = 0; r < 2; r++){
        acc[r][c] = __builtin_amdgcn_mfma_f32_16x16x32_bf16(ah[r], bh, acc[r][c], 0, 0, 0);
        acc[r][c] = __builtin_amdgcn_mfma_f32_16x16x32_bf16(ah[r], bl, acc[r][c], 0, 0, 0);
        acc[r][c] = __builtin_amdgcn_mfma_f32_16x16x32_bf16(al[r], bh, acc[r][c], 0, 0, 0);
      }
    }
    __syncthreads();
  }

  // ---- fused norms: 4-lane reduce ----
  asum += __shfl_xor(asum, 1); asum += __shfl_xor(asum, 2);
  if ((t & 3) == 0 && aok) pnp[(size_t)ks * NPRED + agrow] = asum;
  if (mtile == 0){
    #pragma unroll
    for (int r = 0; r < 3; ++r){
      const int q = t + r * 256;
      float s = bsum[r];
      s += __shfl_xor(s, 1); s += __shfl_xor(s, 2);
      if (q < 640 && (t & 3) == 0) tnp[(size_t)ks * NT + (q >> 2)] = s;
    }
  }

  // ---- store partial products ----
  float* dst = part + (size_t)ks * (NPRED * NT);
  #pragma unroll
  for (int r = 0; r < 2; r++)
    #pragma unroll
    for (int c = 0; c < 5; c++)
      #pragma unroll
      for (int i = 0; i < 4; i++){
        const int grow = mtile * 64 + wr * 32 + r * 16 + fq * 4 + i;
        if (grow < NPRED)
          dst[(size_t)grow * NT + wc * 80 + c * 16 + fr] = acc[r][c][i];
      }
}

// ---------------- reduce norm partials over K-splits ----------------
__global__ __launch_bounds__(256) void norm_reduce(const float* __restrict__ pnp,
                                                   const float* __restrict__ tnp,
                                                   float* __restrict__ pn,
                                                   float* __restrict__ tn, int KS){
  int idx = blockIdx.x * 256 + threadIdx.x;
  if (idx < NPRED){
    float s = 0.f;
    for (int ks = 0; ks < KS; ks++) s += pnp[(size_t)ks * NPRED + idx];
    pn[idx] = s;
  } else if (idx < NPRED + NT){
    int j = idx - NPRED;
    float s = 0.f;
    for (int ks = 0; ks < KS; ks++) s += tnp[(size_t)ks * NT + j];
    tn[j] = s;
  }
}

// ---------------- finalize: reduce K-splits, dice + focal class cost ----------------
__global__ __launch_bounds__(256) void finalize(const float* __restrict__ part, int KS,
                                                const float* __restrict__ pnorm,
                                                const float* __restrict__ tnorm,
                                                const float* __restrict__ logits,
                                                const int* __restrict__ tgt_ids,
                                                float* __restrict__ C){
  int idx = blockIdx.x * 256 + threadIdx.x;
  if (idx >= NPRED * NT) return;
  int pred = idx / NT, t = idx - pred * NT;
  double dot = 0.0;
  for (int ks = 0; ks < KS; ks++) dot += (double)part[(size_t)ks * (NPRED * NT) + idx];
  double num = 2.0 * dot;
  double den = (double)pnorm[pred] + (double)tnorm[t];
  double mask_score = -((num + 1e-4) / (den + 1e-4));
  int cls = tgt_ids[t];
  double x  = (double)logits[pred * NCLS + cls];
  double pl = 1.0 / (1.0 + exp(-x));
  double pos = 0.25 * (1.0 - pl) * (1.0 - pl) * (-log(pl + 1e-8));
  double neg = 0.75 * pl * pl * (-log(1.0 - pl + 1e-8));
  double cv = mask_score * 2.0 + (pos - neg);
  float o = (float)cv;
  if (!isfinite(o)) o = 0.0f;
  C[idx] = o;
}

// ---------------- Hungarian (JV), register-resident, barrier-free inner loop ----------------
// Exact fp64 replica of reference _lsa on the transposed 20x100 block. Per-lane:
// 2 column slots (jA=lane+1, jB=lane+65); u held in lanes 0..19; lookups via shfl.
__global__ __launch_bounds__(64) void hungarian(const float* __restrict__ C,
                                                float* __restrict__ rows_out,
                                                float* __restrict__ cols_out){
  const int img  = blockIdx.x;
  const int lane = threadIdx.x;
  __shared__ float cost[MT][NN];   // f32 is exact: ref converts f32->f64 exactly

  for (int i = lane; i < MT * NN; i += 64){
    int tt = i / NN, p = i - tt * NN;
    cost[tt][p] = C[(size_t)img * NN * NT + (size_t)p * NT + img * MT + tt];
  }
  __syncthreads();

  const double INF = 1e18;
  const int jA = lane + 1, jB = lane + 65;
  const bool hasB = (jB <= NN);

  double vA = 0.0, vB = 0.0, u_reg = 0.0;
  int pA = 0, pB = 0;

  for (int i = 1; i <= MT; i++){
    double minA = INF, minB = INF;
    int wayA = 0, wayB = 0;
    bool usedA = false, usedB = false, inTree = false;
    int j0 = 0;

    while (true){
      int i0;
      if (j0 == 0) i0 = i;
      else {
        int pa = __shfl(pA, (j0 - 1) & 63);
        int pb = __shfl(pB, (j0 - 65) & 63);
        i0 = (j0 <= 64) ? pa : pb;
        if (j0 <= 64){ if (lane == j0 - 1)  usedA = true; }
        else         { if (lane == j0 - 65) usedB = true; }
      }
      if (lane == i0 - 1) inTree = true;
      double ui0 = __shfl(u_reg, i0 - 1);
      // relax free columns (same fp64 elementwise ops as reference)
      if (!usedA){
        double cur = (double)cost[i0 - 1][jA - 1] - ui0 - vA;
        if (cur < minA){ minA = cur; wayA = j0; }
      }
      if (hasB && !usedB){
        double cur = (double)cost[i0 - 1][jB - 1] - ui0 - vB;
        if (cur < minB){ minB = cur; wayB = j0; }
      }
      // masked argmin, np.argmin tie-break (smallest index)
      double bv = usedA ? INF : minA; int bi = jA;
      if (hasB){
        double v2 = usedB ? INF : minB;
        if (v2 < bv){ bv = v2; bi = jB; }
      }
      #pragma unroll
      for (int off = 32; off >= 1; off >>= 1){
        double ov = __shfl_xor(bv, off);
        int    oi = __shfl_xor(bi, off);
        if (ov < bv || (ov == bv && oi < bi)){ bv = ov; bi = oi; }
      }
      const double delta = bv;
      const int j1 = bi;
      // dual updates (u for tree rows incl. current i; v for used cols; minv for free)
      if (lane < MT && inTree) u_reg += delta;
      if (usedA) vA -= delta; else minA -= delta;
      if (hasB){ if (usedB) vB -= delta; else minB -= delta; }
      j0 = j1;
      int pj = (j0 <= 64) ? __shfl(pA, (j0 - 1) & 63) : __shfl(pB, (j0 - 65) & 63);
      if (pj == 0) break;
    }
    // augmenting path flip via shfl lookups (p[j] = p[way[j]] along chain)
    int j = j0;
    while (true){
      int wjA = __shfl(wayA, (j - 1) & 63);
      int wjB = __shfl(wayB, (j - 65) & 63);
      int wj = (j <= 64) ? wjA : wjB;
      int pv;
      if (wj == 0) pv = i;
      else {
        int pa = __shfl(pA, (wj - 1) & 63);
        int pb = __shfl(pB, (wj - 65) & 63);
        pv = (wj <= 64) ? pa : pb;
      }
      if (j <= 64){ if (lane == j - 1)  pA = pv; }
      else        { if (lane == j - 65) pB = pv; }
      j = wj;
      if (j == 0) break;
    }
  }

  // emit pairs sorted by pred (column) index via ballot compaction
  unsigned long long mA = __ballot(pA != 0);
  unsigned long long mB = __ballot(hasB && pB != 0);
  unsigned long long lt = (1ull << lane) - 1ull;
  if (pA != 0){
    int rank = __popcll(mA & lt);
    rows_out[img * MT + rank] = (float)(jA - 1);
    cols_out[img * MT + rank] = (float)(pA - 1);
  }
  if (hasB && pB != 0){
    int rank = __popcll(mA) + __popcll(mB & lt);
    rows_out[img * MT + rank] = (float)(jB - 1);
    cols_out[img * MT + rank] = (float)(pB - 1);
  }
}

extern "C" void kernel_launch(void* const* d_in, const int* in_sizes, int n_in,
                              void* d_out, int out_size, void* d_ws, size_t ws_size,
                              hipStream_t stream) {
  const float* pm     = (const float*)d_in[0];   // (8,100,160,160)
  const float* logits = (const float*)d_in[1];   // (8,100,80)
  const float* tm     = (const float*)d_in[2];   // (160,160,160)
  const int*   tids   = (const int*)d_in[3];     // (160,)

  float* C        = (float*)d_out;               // 128000
  float* rows_out = C + NPRED * NT;
  float* cols_out = rows_out + NB * MT;

  // pick largest K-split that fits in workspace (Kc = HW/KS, divisible by 32)
  static const int ks_opts[] = {100, 50, 25, 10, 5, 2, 1};
  int KS = 1; size_t part_off = 0;
  for (int oi = 0; oi < 7; oi++){
    int o = ks_opts[oi];
    size_t norms = (size_t)o * (NPRED + NT) * 4 + (NPRED + NT) * 4;
    size_t po = (norms + 255) & ~(size_t)255;
    size_t need = po + (size_t)o * (NPRED * NT) * 4;
    if (need <= ws_size){ KS = o; part_off = po; break; }
  }
  char* ws = (char*)d_ws;
  float* pnp   = (float*)ws;                                    // [KS][800]
  float* tnp   = (float*)(ws + (size_t)KS * NPRED * 4);         // [KS][160]
  float* pnorm = (float*)(ws + (size_t)KS * (NPRED + NT) * 4);  // [800]
  float* tnorm = pnorm + NPRED;                                 // [160]
  float* part  = (float*)(ws + part_off);                       // [KS][800*160]

  const int Kc = HW / KS;
  const int ksteps = Kc / 32;

  gemm_split<<<dim3(13, KS), 256, 0, stream>>>(pm, tm, part, pnp, tnp, Kc, ksteps);
  norm_reduce<<<4, 256, 0, stream>>>(pnp, tnp, pnorm, tnorm, KS);
  finalize<<<(NPRED * NT + 255) / 256, 256, 0, stream>>>(part, KS, pnorm, tnorm, logits, tids, C);
  hungarian<<<NB, 64, 0, stream>>>(C, rows_out, cols_out);
}

// Round 4
// 150.283 us; speedup vs baseline: 1.0649x; 1.0649x over previous
//
#include <hip/hip_runtime.h>
#include <math.h>

#define NB    8
#define NN    100
#define NPRED (NB*NN)     // 800
#define MT    20
#define NT    (NB*MT)     // 160
#define HW    25600
#define NCLS  80
#define CNT   (NPRED*NT)  // 128000

typedef float  f32x4  __attribute__((ext_vector_type(4)));
typedef short  short8 __attribute__((ext_vector_type(8)));
typedef unsigned short u16x8 __attribute__((ext_vector_type(8)));

static __device__ __forceinline__ unsigned short f2bf_rne(float f){
  unsigned u = __float_as_uint(f);
  return (unsigned short)((u + 0x7fffu + ((u >> 16) & 1u)) >> 16);
}

// ---------------- split-bf16 MFMA GEMM, 96x160x64, reg-prefetch pipeline ----------------
// 4 waves 2x2, wave tile 48x80 (3x5 frags of 16x16x32). XOR-swizzled LDS (0 conflicts, r2).
__global__ __launch_bounds__(256, 2)
void gemm_split(const float* __restrict__ A, const float* __restrict__ Bm,
                float* __restrict__ part, float* __restrict__ pnp,
                float* __restrict__ tnp, int Kc, int ksteps){
  __shared__ unsigned short sAhi[96*64], sAlo[96*64];
  __shared__ unsigned short sBhi[160*64], sBlo[160*64];

  const int t     = threadIdx.x;
  const int mtile = blockIdx.x, ks = blockIdx.y;
  const int lane  = t & 63, w = t >> 6;
  const int wr = w >> 1, wc = w & 1;
  const int fr = lane & 15, fq = lane >> 4;
  const int r0 = t >> 3, ksl = t & 7;
  const int kbase = ks * Kc;

  f32x4 acc[3][5];
  #pragma unroll
  for (int r = 0; r < 3; r++)
    #pragma unroll
    for (int c = 0; c < 5; c++) acc[r][c] = (f32x4){0.f,0.f,0.f,0.f};

  float asum[3] = {0.f,0.f,0.f};
  float tsum[5] = {0.f,0.f,0.f,0.f,0.f};

  float4 av0[3], av1[3], bv0[5], bv1[5];
  bool aok[3];
  #pragma unroll
  for (int j = 0; j < 3; j++) aok[j] = (mtile * 96 + r0 + 32 * j) < NPRED;

  // prologue: load step 0
  {
    const int k0 = kbase;
    #pragma unroll
    for (int j = 0; j < 3; j++){
      if (aok[j]){
        const float4* p = (const float4*)(A + (size_t)(mtile*96 + r0 + 32*j) * HW + k0 + ksl*8);
        av0[j] = p[0]; av1[j] = p[1];
      } else { av0[j] = (float4){0,0,0,0}; av1[j] = (float4){0,0,0,0}; }
    }
    #pragma unroll
    for (int j = 0; j < 5; j++){
      const float4* p = (const float4*)(Bm + (size_t)(r0 + 32*j) * HW + k0 + ksl*8);
      bv0[j] = p[0]; bv1[j] = p[1];
    }
  }

  for (int step = 0; step < ksteps; ++step){
    // ---- convert prefetched regs -> LDS ----
    #pragma unroll
    for (int j = 0; j < 3; ++j){
      float v[8];
      v[0]=av0[j].x; v[1]=av0[j].y; v[2]=av0[j].z; v[3]=av0[j].w;
      v[4]=av1[j].x; v[5]=av1[j].y; v[6]=av1[j].z; v[7]=av1[j].w;
      u16x8 H, L;
      #pragma unroll
      for (int i = 0; i < 8; i++){
        asum[j] += v[i]*v[i];
        unsigned u = __float_as_uint(v[i]);
        H[i] = (unsigned short)(u >> 16);
        L[i] = f2bf_rne(v[i] - __uint_as_float(u & 0xffff0000u));
      }
      const int rl = r0 + 32*j;
      const int eo = rl * 64 + ((ksl ^ (rl & 7)) << 3);
      *(u16x8*)&sAhi[eo] = H;
      *(u16x8*)&sAlo[eo] = L;
    }
    #pragma unroll
    for (int j = 0; j < 5; ++j){
      float v[8];
      v[0]=bv0[j].x; v[1]=bv0[j].y; v[2]=bv0[j].z; v[3]=bv0[j].w;
      v[4]=bv1[j].x; v[5]=bv1[j].y; v[6]=bv1[j].z; v[7]=bv1[j].w;
      u16x8 H, L;
      #pragma unroll
      for (int i = 0; i < 8; i++){
        tsum[j] += v[i]*v[i];
        unsigned u = __float_as_uint(v[i]);
        H[i] = (unsigned short)(u >> 16);
        L[i] = f2bf_rne(v[i] - __uint_as_float(u & 0xffff0000u));
      }
      const int rl = r0 + 32*j;
      const int eo = rl * 64 + ((ksl ^ (rl & 7)) << 3);
      *(u16x8*)&sBhi[eo] = H;
      *(u16x8*)&sBlo[eo] = L;
    }
    __syncthreads();
    // ---- issue next step's global loads (hide under MFMAs) ----
    if (step + 1 < ksteps){
      const int k0 = kbase + (step + 1) * 64;
      #pragma unroll
      for (int j = 0; j < 3; j++){
        if (aok[j]){
          const float4* p = (const float4*)(A + (size_t)(mtile*96 + r0 + 32*j) * HW + k0 + ksl*8);
          av0[j] = p[0]; av1[j] = p[1];
        }
      }
      #pragma unroll
      for (int j = 0; j < 5; j++){
        const float4* p = (const float4*)(Bm + (size_t)(r0 + 32*j) * HW + k0 + ksl*8);
        bv0[j] = p[0]; bv1[j] = p[1];
      }
    }
    // ---- MFMA: 2 kk halves x (3x5 frags) x 3 precision terms ----
    #pragma unroll
    for (int kk = 0; kk < 2; ++kk){
      const int slot = kk * 4 + fq;
      const int swz  = (slot ^ (fr & 7)) << 3;
      short8 ah[3], al[3], bh[5], bl[5];
      #pragma unroll
      for (int r = 0; r < 3; r++){
        const int eo = (wr*48 + r*16 + fr) * 64 + swz;
        ah[r] = *(const short8*)&sAhi[eo];
        al[r] = *(const short8*)&sAlo[eo];
      }
      #pragma unroll
      for (int c = 0; c < 5; c++){
        const int eo = (wc*80 + c*16 + fr) * 64 + swz;
        bh[c] = *(const short8*)&sBhi[eo];
        bl[c] = *(const short8*)&sBlo[eo];
      }
      #pragma unroll
      for (int r = 0; r < 3; r++)
        #pragma unroll
        for (int c = 0; c < 5; c++){
          acc[r][c] = __builtin_amdgcn_mfma_f32_16x16x32_bf16(ah[r], bh[c], acc[r][c], 0, 0, 0);
          acc[r][c] = __builtin_amdgcn_mfma_f32_16x16x32_bf16(ah[r], bl[c], acc[r][c], 0, 0, 0);
          acc[r][c] = __builtin_amdgcn_mfma_f32_16x16x32_bf16(al[r], bh[c], acc[r][c], 0, 0, 0);
        }
    }
    __syncthreads();
  }

  // ---- fused norms: 8-lane reduce over ksl ----
  #pragma unroll
  for (int j = 0; j < 3; ++j){
    float s = asum[j];
    s += __shfl_xor(s, 1); s += __shfl_xor(s, 2); s += __shfl_xor(s, 4);
    const int grow = mtile*96 + r0 + 32*j;
    if ((t & 7) == 0 && grow < NPRED) pnp[(size_t)ks * NPRED + grow] = s;
  }
  if (mtile == 0){
    #pragma unroll
    for (int j = 0; j < 5; ++j){
      float s = tsum[j];
      s += __shfl_xor(s, 1); s += __shfl_xor(s, 2); s += __shfl_xor(s, 4);
      if ((t & 7) == 0) tnp[(size_t)ks * NT + r0 + 32*j] = s;
    }
  }

  // ---- store partial products ----
  float* dst = part + (size_t)ks * CNT;
  #pragma unroll
  for (int r = 0; r < 3; r++)
    #pragma unroll
    for (int c = 0; c < 5; c++)
      #pragma unroll
      for (int i = 0; i < 4; i++){
        const int grow = mtile*96 + wr*48 + r*16 + fq*4 + i;
        if (grow < NPRED)
          dst[(size_t)grow * NT + wc*80 + c*16 + fr] = acc[r][c][i];
      }
}

// ---------------- reduce norm partials ----------------
__global__ __launch_bounds__(256) void norm_reduce(const float* __restrict__ pnp,
                                                   const float* __restrict__ tnp,
                                                   float* __restrict__ pn,
                                                   float* __restrict__ tn, int KS){
  int idx = blockIdx.x * 256 + threadIdx.x;
  if (idx < NPRED){
    float s = 0.f;
    for (int ks = 0; ks < KS; ks++) s += pnp[(size_t)ks * NPRED + idx];
    pn[idx] = s;
  } else if (idx < NPRED + NT){
    int j = idx - NPRED;
    float s = 0.f;
    for (int ks = 0; ks < KS; ks++) s += tnp[(size_t)ks * NT + j];
    tn[j] = s;
  }
}

// shared fp64 reduction (identical op order in both consumers -> bit-exact)
static __device__ __forceinline__ double ks_dot(const float* __restrict__ part, int KS, size_t idx){
  const float* p = part + idx;
  double d0=0.0, d1=0.0, d2=0.0, d3=0.0;
  int ks = 0;
  for (; ks + 4 <= KS; ks += 4){
    d0 += (double)p[(size_t)(ks+0) * CNT];
    d1 += (double)p[(size_t)(ks+1) * CNT];
    d2 += (double)p[(size_t)(ks+2) * CNT];
    d3 += (double)p[(size_t)(ks+3) * CNT];
  }
  for (; ks < KS; ks++) d0 += (double)p[(size_t)ks * CNT];
  return (d0 + d1) + (d2 + d3);
}

static __device__ __forceinline__ float cost_entry(double dot, double pn, double tn, double x){
  double num = 2.0 * dot;
  double den = pn + tn;
  double mask_score = -((num + 1e-4) / (den + 1e-4));
  double pl = 1.0 / (1.0 + exp(-x));
  double pos = 0.25 * (1.0 - pl) * (1.0 - pl) * (-log(pl + 1e-8));
  double neg = 0.75 * pl * pl * (-log(1.0 - pl + 1e-8));
  double cv = mask_score * 2.0 + (pos - neg);
  float o = (float)cv;
  if (!isfinite(o)) o = 0.0f;
  return o;
}

// ---------------- fused finalize + hungarian ----------------
// blocks [0,500): finalize C. blocks [500,508): per-image JV (computes own cost block).
__global__ __launch_bounds__(256)
void finalize_hung(const float* __restrict__ part, int KS,
                   const float* __restrict__ pnorm, const float* __restrict__ tnorm,
                   const float* __restrict__ logits, const int* __restrict__ tgt_ids,
                   float* __restrict__ C, float* __restrict__ rows_out,
                   float* __restrict__ cols_out){
  const int blk = blockIdx.x;
  if (blk < 500){
    int idx = blk * 256 + threadIdx.x;
    int pred = idx / NT, tt = idx - pred * NT;
    double dot = ks_dot(part, KS, idx);
    double x = (double)logits[pred * NCLS + tgt_ids[tt]];
    C[idx] = cost_entry(dot, (double)pnorm[pred], (double)tnorm[tt], x);
    return;
  }

  const int img = blk - 500;
  const int t = threadIdx.x;
  __shared__ float cost[MT][NN];

  // compute own 20x100 cost block (bit-identical to finalize's C values)
  for (int e = t; e < MT * NN; e += 256){
    int p = e / MT, tt = e - p * MT;
    int gp = img * NN + p, gt = img * MT + tt;
    size_t base = (size_t)gp * NT + gt;
    double dot = ks_dot(part, KS, base);
    double x = (double)logits[gp * NCLS + tgt_ids[gt]];
    cost[tt][p] = cost_entry(dot, (double)pnorm[gp], (double)tnorm[gt], x);
  }
  __syncthreads();
  if (t >= 64) return;

  const int lane = t;
  const double INF = 1e18;
  const int jA = lane + 1, jB = lane + 65;
  const bool hasB = (jB <= NN);

  double vA = 0.0, vB = 0.0, u_reg = 0.0;
  int pA = 0, pB = 0;

  for (int i = 1; i <= MT; i++){
    double minA = INF, minB = INF;
    int wayA = 0, wayB = 0;
    bool usedA = false, usedB = false, inTree = false;
    int j0 = 0;

    while (true){
      int i0;
      if (j0 == 0) i0 = i;
      else {
        int pa = __shfl(pA, (j0 - 1) & 63);
        int pb = __shfl(pB, (j0 - 65) & 63);
        i0 = (j0 <= 64) ? pa : pb;
        if (j0 <= 64){ if (lane == j0 - 1)  usedA = true; }
        else         { if (lane == j0 - 65) usedB = true; }
      }
      if (lane == i0 - 1) inTree = true;
      double ui0 = __shfl(u_reg, i0 - 1);
      if (!usedA){
        double cur = (double)cost[i0 - 1][jA - 1] - ui0 - vA;
        if (cur < minA){ minA = cur; wayA = j0; }
      }
      if (hasB && !usedB){
        double cur = (double)cost[i0 - 1][jB - 1] - ui0 - vB;
        if (cur < minB){ minB = cur; wayB = j0; }
      }
      double bv = usedA ? INF : minA; int bi = jA;
      if (hasB){
        double v2 = usedB ? INF : minB;
        if (v2 < bv){ bv = v2; bi = jB; }
      }
      #pragma unroll
      for (int off = 32; off >= 1; off >>= 1){
        double ov = __shfl_xor(bv, off);
        int    oi = __shfl_xor(bi, off);
        if (ov < bv || (ov == bv && oi < bi)){ bv = ov; bi = oi; }
      }
      const double delta = bv;
      const int j1 = bi;
      if (lane < MT && inTree) u_reg += delta;
      if (usedA) vA -= delta; else minA -= delta;
      if (hasB){ if (usedB) vB -= delta; else minB -= delta; }
      j0 = j1;
      int pj = (j0 <= 64) ? __shfl(pA, (j0 - 1) & 63) : __shfl(pB, (j0 - 65) & 63);
      if (pj == 0) break;
    }
    int j = j0;
    while (true){
      int wjA = __shfl(wayA, (j - 1) & 63);
      int wjB = __shfl(wayB, (j - 65) & 63);
      int wj = (j <= 64) ? wjA : wjB;
      int pv;
      if (wj == 0) pv = i;
      else {
        int pa = __shfl(pA, (wj - 1) & 63);
        int pb = __shfl(pB, (wj - 65) & 63);
        pv = (wj <= 64) ? pa : pb;
      }
      if (j <= 64){ if (lane == j - 1)  pA = pv; }
      else        { if (lane == j - 65) pB = pv; }
      j = wj;
      if (j == 0) break;
    }
  }

  unsigned long long mA = __ballot(pA != 0);
  unsigned long long mB = __ballot(hasB && pB != 0);
  unsigned long long lt = (1ull << lane) - 1ull;
  if (pA != 0){
    int rank = __popcll(mA & lt);
    rows_out[img * MT + rank] = (float)(jA - 1);
    cols_out[img * MT + rank] = (float)(pA - 1);
  }
  if (hasB && pB != 0){
    int rank = __popcll(mA) + __popcll(mB & lt);
    rows_out[img * MT + rank] = (float)(jB - 1);
    cols_out[img * MT + rank] = (float)(pB - 1);
  }
}

extern "C" void kernel_launch(void* const* d_in, const int* in_sizes, int n_in,
                              void* d_out, int out_size, void* d_ws, size_t ws_size,
                              hipStream_t stream) {
  const float* pm     = (const float*)d_in[0];
  const float* logits = (const float*)d_in[1];
  const float* tm     = (const float*)d_in[2];
  const int*   tids   = (const int*)d_in[3];

  float* C        = (float*)d_out;
  float* rows_out = C + CNT;
  float* cols_out = rows_out + NB * MT;

  static const int ks_opts[] = {50, 25, 10, 5, 2, 1};   // Kc divisible by 64
  int KS = 1; size_t part_off = 0;
  for (int oi = 0; oi < 6; oi++){
    int o = ks_opts[oi];
    size_t norms = (size_t)o * (NPRED + NT) * 4 + (NPRED + NT) * 4;
    size_t po = (norms + 255) & ~(size_t)255;
    size_t need = po + (size_t)o * CNT * 4;
    if (need <= ws_size){ KS = o; part_off = po; break; }
  }
  char* ws = (char*)d_ws;
  float* pnp   = (float*)ws;
  float* tnp   = (float*)(ws + (size_t)KS * NPRED * 4);
  float* pnorm = (float*)(ws + (size_t)KS * (NPRED + NT) * 4);
  float* tnorm = pnorm + NPRED;
  float* part  = (float*)(ws + part_off);

  const int Kc = HW / KS;
  const int ksteps = Kc / 64;

  gemm_split<<<dim3(9, KS), 256, 0, stream>>>(pm, tm, part, pnp, tnp, Kc, ksteps);
  norm_reduce<<<4, 256, 0, stream>>>(pnp, tnp, pnorm, tnorm, KS);
  finalize_hung<<<508, 256, 0, stream>>>(part, KS, pnorm, tnorm, logits, tids,
                                         C, rows_out, cols_out);
}

// Round 5
// 126.106 us; speedup vs baseline: 1.2691x; 1.1917x over previous
//
#include <hip/hip_runtime.h>
#include <math.h>

#define NB    8
#define NN    100
#define NPRED (NB*NN)     // 800
#define MT    20
#define NT    (NB*MT)     // 160
#define HW    25600
#define NCLS  80
#define CNT   (NPRED*NT)  // 128000

typedef float  f32x4  __attribute__((ext_vector_type(4)));
typedef short  short8 __attribute__((ext_vector_type(8)));
typedef unsigned short u16x8 __attribute__((ext_vector_type(8)));

static __device__ __forceinline__ unsigned short f2bf_rne(float f){
  unsigned u = __float_as_uint(f);
  return (unsigned short)((u + 0x7fffu + ((u >> 16) & 1u)) >> 16);
}

// ---------------- bf16 MFMA GEMM, 64x160x64 tile, XOR-swizzled LDS, fused norms ----------------
// 4 waves 2x2, wave tile 32x80 (2x5 frags of 16x16x32). RNE-bf16 inputs (C err ~2e-5, safe).
__global__ __launch_bounds__(256, 4)
void gemm_bf16(const float* __restrict__ A, const float* __restrict__ Bm,
               float* __restrict__ part, float* __restrict__ pnp,
               float* __restrict__ tnp, int Kc, int ksteps){
  __shared__ unsigned short sA[64*64];
  __shared__ unsigned short sB[160*64];

  const int t     = threadIdx.x;
  const int mtile = blockIdx.x, ks = blockIdx.y;
  const int lane  = t & 63, w = t >> 6;
  const int wr = w >> 1, wc = w & 1;
  const int fr = lane & 15, fq = lane >> 4;
  const int r0 = t >> 3, ksl = t & 7;
  const int kbase = ks * Kc;

  f32x4 acc[2][5];
  #pragma unroll
  for (int r = 0; r < 2; r++)
    #pragma unroll
    for (int c = 0; c < 5; c++) acc[r][c] = (f32x4){0.f,0.f,0.f,0.f};

  float asum[2] = {0.f,0.f};
  float tsum[5] = {0.f,0.f,0.f,0.f,0.f};

  bool aok[2];
  #pragma unroll
  for (int j = 0; j < 2; j++) aok[j] = (mtile * 64 + r0 + 32 * j) < NPRED;

  for (int step = 0; step < ksteps; ++step){
    const int k0 = kbase + step * 64;
    // ---- stage A (64x64): 2 row-slots of 8 k each ----
    #pragma unroll
    for (int j = 0; j < 2; ++j){
      const int rl = r0 + 32 * j;
      float v[8];
      if (aok[j]){
        const float4* p = (const float4*)(A + (size_t)(mtile*64 + rl) * HW + k0 + ksl*8);
        float4 x0 = p[0], x1 = p[1];
        v[0]=x0.x; v[1]=x0.y; v[2]=x0.z; v[3]=x0.w;
        v[4]=x1.x; v[5]=x1.y; v[6]=x1.z; v[7]=x1.w;
      } else {
        #pragma unroll
        for (int i = 0; i < 8; i++) v[i] = 0.f;
      }
      u16x8 H;
      #pragma unroll
      for (int i = 0; i < 8; i++){
        asum[j] += v[i]*v[i];
        H[i] = f2bf_rne(v[i]);
      }
      const int eo = rl * 64 + ((ksl ^ (rl & 7)) << 3);
      *(u16x8*)&sA[eo] = H;
    }
    // ---- stage B (160x64): 5 row-slots ----
    #pragma unroll
    for (int j = 0; j < 5; ++j){
      const int rl = r0 + 32 * j;
      const float4* p = (const float4*)(Bm + (size_t)rl * HW + k0 + ksl*8);
      float4 x0 = p[0], x1 = p[1];
      float v[8];
      v[0]=x0.x; v[1]=x0.y; v[2]=x0.z; v[3]=x0.w;
      v[4]=x1.x; v[5]=x1.y; v[6]=x1.z; v[7]=x1.w;
      u16x8 H;
      #pragma unroll
      for (int i = 0; i < 8; i++){
        tsum[j] += v[i]*v[i];
        H[i] = f2bf_rne(v[i]);
      }
      const int eo = rl * 64 + ((ksl ^ (rl & 7)) << 3);
      *(u16x8*)&sB[eo] = H;
    }
    __syncthreads();
    // ---- MFMA: 2 kk halves x (2x5 frags) ----
    #pragma unroll
    for (int kk = 0; kk < 2; ++kk){
      const int slot = kk * 4 + fq;
      const int swz  = (slot ^ (fr & 7)) << 3;
      short8 a[2], b[5];
      #pragma unroll
      for (int r = 0; r < 2; r++)
        a[r] = *(const short8*)&sA[(wr*32 + r*16 + fr) * 64 + swz];
      #pragma unroll
      for (int c = 0; c < 5; c++)
        b[c] = *(const short8*)&sB[(wc*80 + c*16 + fr) * 64 + swz];
      #pragma unroll
      for (int r = 0; r < 2; r++)
        #pragma unroll
        for (int c = 0; c < 5; c++)
          acc[r][c] = __builtin_amdgcn_mfma_f32_16x16x32_bf16(a[r], b[c], acc[r][c], 0, 0, 0);
    }
    __syncthreads();
  }

  // ---- fused norms: 8-lane reduce over ksl ----
  #pragma unroll
  for (int j = 0; j < 2; ++j){
    float s = asum[j];
    s += __shfl_xor(s, 1); s += __shfl_xor(s, 2); s += __shfl_xor(s, 4);
    const int grow = mtile*64 + r0 + 32*j;
    if ((t & 7) == 0 && grow < NPRED) pnp[(size_t)ks * NPRED + grow] = s;
  }
  if (mtile == 0){
    #pragma unroll
    for (int j = 0; j < 5; ++j){
      float s = tsum[j];
      s += __shfl_xor(s, 1); s += __shfl_xor(s, 2); s += __shfl_xor(s, 4);
      if ((t & 7) == 0) tnp[(size_t)ks * NT + r0 + 32*j] = s;
    }
  }

  // ---- store partials ----
  float* dst = part + (size_t)ks * CNT;
  #pragma unroll
  for (int r = 0; r < 2; r++)
    #pragma unroll
    for (int c = 0; c < 5; c++)
      #pragma unroll
      for (int i = 0; i < 4; i++){
        const int grow = mtile*64 + wr*32 + r*16 + fq*4 + i;
        if (grow < NPRED)
          dst[(size_t)grow * NT + wc*80 + c*16 + fr] = acc[r][c][i];
      }
}

// ---------------- reduce norm partials ----------------
__global__ __launch_bounds__(256) void norm_reduce(const float* __restrict__ pnp,
                                                   const float* __restrict__ tnp,
                                                   float* __restrict__ pn,
                                                   float* __restrict__ tn, int KS){
  int idx = blockIdx.x * 256 + threadIdx.x;
  if (idx < NPRED){
    float s = 0.f;
    for (int ks = 0; ks < KS; ks++) s += pnp[(size_t)ks * NPRED + idx];
    pn[idx] = s;
  } else if (idx < NPRED + NT){
    int j = idx - NPRED;
    float s = 0.f;
    for (int ks = 0; ks < KS; ks++) s += tnp[(size_t)ks * NT + j];
    tn[j] = s;
  }
}

// ---------------- finalize: reduce K-splits, dice + focal class cost ----------------
__global__ __launch_bounds__(256) void finalize(const float* __restrict__ part, int KS,
                                                const float* __restrict__ pnorm,
                                                const float* __restrict__ tnorm,
                                                const float* __restrict__ logits,
                                                const int* __restrict__ tgt_ids,
                                                float* __restrict__ C){
  int idx = blockIdx.x * 256 + threadIdx.x;
  int pred = idx / NT, tt = idx - pred * NT;
  const float* p = part + idx;
  double d0=0.0, d1=0.0, d2=0.0, d3=0.0;
  int ks = 0;
  for (; ks + 4 <= KS; ks += 4){
    d0 += (double)p[(size_t)(ks+0) * CNT];
    d1 += (double)p[(size_t)(ks+1) * CNT];
    d2 += (double)p[(size_t)(ks+2) * CNT];
    d3 += (double)p[(size_t)(ks+3) * CNT];
  }
  for (; ks < KS; ks++) d0 += (double)p[(size_t)ks * CNT];
  double dot = (d0 + d1) + (d2 + d3);
  double num = 2.0 * dot;
  double den = (double)pnorm[pred] + (double)tnorm[tt];
  double mask_score = -((num + 1e-4) / (den + 1e-4));
  double x = (double)logits[pred * NCLS + tgt_ids[tt]];
  double pl = 1.0 / (1.0 + exp(-x));
  double pos = 0.25 * (1.0 - pl) * (1.0 - pl) * (-log(pl + 1e-8));
  double neg = 0.75 * pl * pl * (-log(1.0 - pl + 1e-8));
  double cv = mask_score * 2.0 + (pos - neg);
  float o = (float)cv;
  if (!isfinite(o)) o = 0.0f;
  C[idx] = o;
}

// ---------------- Hungarian (JV), fp32, register cost columns, DPP argmin ----------------
static __device__ __forceinline__ float sel20(const float c[20], int k){
  // static-index binary select tree (k in [0,20))
  const bool b0 = k & 1, b1 = k & 2;
  float t0 = b0 ? c[1]  : c[0],  t1 = b0 ? c[3]  : c[2];
  float t2 = b0 ? c[5]  : c[4],  t3 = b0 ? c[7]  : c[6];
  float t4 = b0 ? c[9]  : c[8],  t5 = b0 ? c[11] : c[10];
  float t6 = b0 ? c[13] : c[12], t7 = b0 ? c[15] : c[14];
  float t8 = b0 ? c[17] : c[16], t9 = b0 ? c[19] : c[18];
  float e0 = b1 ? t1 : t0, e1 = b1 ? t3 : t2, e2 = b1 ? t5 : t4;
  float e3 = b1 ? t7 : t6, e4 = b1 ? t9 : t8;
  const int hi = k >> 2;
  const bool h0 = hi & 1, h1 = hi & 2, h2 = hi & 4;
  float g0 = h0 ? e1 : e0, g1 = h0 ? e3 : e2;
  float m0 = h1 ? g1 : g0;
  return h2 ? e4 : m0;
}

#define DPP_STEP(ctrl) { \
  float pv = __uint_as_float((unsigned)__builtin_amdgcn_update_dpp(0, (int)__float_as_uint(v), ctrl, 0xF, 0xF, true)); \
  int pi = __builtin_amdgcn_update_dpp(0, i, ctrl, 0xF, 0xF, true); \
  if (pv < v || (pv == v && pi < i)){ v = pv; i = pi; } }

static __device__ __forceinline__ void argmin64(float &v, int &i){
  DPP_STEP(0xB1)   // quad_perm xor1
  DPP_STEP(0x4E)   // quad_perm xor2
  DPP_STEP(0x124)  // row_ror:4
  DPP_STEP(0x128)  // row_ror:8
  { float pv = __shfl_xor(v, 16); int pi = __shfl_xor(i, 16);
    if (pv < v || (pv == v && pi < i)){ v = pv; i = pi; } }
  { float pv = __shfl_xor(v, 32); int pi = __shfl_xor(i, 32);
    if (pv < v || (pv == v && pi < i)){ v = pv; i = pi; } }
}

__global__ __launch_bounds__(64) void hungarian(const float* __restrict__ C,
                                                float* __restrict__ rows_out,
                                                float* __restrict__ cols_out){
  const int img  = blockIdx.x;
  const int lane = threadIdx.x;
  const int jA = lane + 1, jB = lane + 65;
  const bool hasB = (jB <= NN);

  // cost columns in registers: ca = column (pred) lane, cb = column lane+64
  float ca[20], cb[20];
  {
    const float* basep = C + (size_t)img * NN * NT + (size_t)lane * NT + img * MT;
    #pragma unroll
    for (int r = 0; r < 5; r++){
      float4 x = *(const float4*)(basep + r*4);
      ca[r*4+0]=x.x; ca[r*4+1]=x.y; ca[r*4+2]=x.z; ca[r*4+3]=x.w;
    }
    if (hasB){
      const float* basep2 = basep + (size_t)64 * NT;
      #pragma unroll
      for (int r = 0; r < 5; r++){
        float4 x = *(const float4*)(basep2 + r*4);
        cb[r*4+0]=x.x; cb[r*4+1]=x.y; cb[r*4+2]=x.z; cb[r*4+3]=x.w;
      }
    } else {
      #pragma unroll
      for (int r = 0; r < 20; r++) cb[r] = 0.f;
    }
  }

  const float INF = 1e30f;
  float vA = 0.f, vB = 0.f, u_reg = 0.f;
  int pA = 0, pB = 0;

  for (int i = 1; i <= MT; i++){
    float minA = INF, minB = INF;
    int wayA = 0, wayB = 0;
    bool usedA = false, usedB = false, inTree = false;
    int j0 = 0;

    while (true){
      int i0;
      if (j0 == 0) i0 = i;
      else {
        int pa = __shfl(pA, (j0 - 1) & 63);
        int pb = __shfl(pB, (j0 - 65) & 63);
        i0 = (j0 <= 64) ? pa : pb;
        if (j0 <= 64){ if (lane == j0 - 1)  usedA = true; }
        else         { if (lane == j0 - 65) usedB = true; }
      }
      if (lane == i0 - 1) inTree = true;
      float ui0 = __shfl(u_reg, i0 - 1);
      // relax free columns
      if (!usedA){
        float cur = sel20(ca, i0 - 1) - ui0 - vA;
        if (cur < minA){ minA = cur; wayA = j0; }
      }
      if (hasB && !usedB){
        float cur = sel20(cb, i0 - 1) - ui0 - vB;
        if (cur < minB){ minB = cur; wayB = j0; }
      }
      // masked argmin (lowest index on tie)
      float bv = usedA ? INF : minA; int bi = jA;
      if (hasB){
        float v2 = usedB ? INF : minB;
        if (v2 < bv){ bv = v2; bi = jB; }
      }
      argmin64(bv, bi);
      const float delta = bv;
      const int j1 = bi;
      if (lane < MT && inTree) u_reg += delta;
      if (usedA) vA -= delta; else minA -= delta;
      if (hasB){ if (usedB) vB -= delta; else minB -= delta; }
      j0 = j1;
      int pj = (j0 <= 64) ? __shfl(pA, (j0 - 1) & 63) : __shfl(pB, (j0 - 65) & 63);
      if (pj == 0) break;
    }
    // augmenting path flip
    int j = j0;
    while (true){
      int wjA = __shfl(wayA, (j - 1) & 63);
      int wjB = __shfl(wayB, (j - 65) & 63);
      int wj = (j <= 64) ? wjA : wjB;
      int pv;
      if (wj == 0) pv = i;
      else {
        int pa = __shfl(pA, (wj - 1) & 63);
        int pb = __shfl(pB, (wj - 65) & 63);
        pv = (wj <= 64) ? pa : pb;
      }
      if (j <= 64){ if (lane == j - 1)  pA = pv; }
      else        { if (lane == j - 65) pB = pv; }
      j = wj;
      if (j == 0) break;
    }
  }

  unsigned long long mA = __ballot(pA != 0);
  unsigned long long mB = __ballot(hasB && pB != 0);
  unsigned long long lt = (1ull << lane) - 1ull;
  if (pA != 0){
    int rank = __popcll(mA & lt);
    rows_out[img * MT + rank] = (float)(jA - 1);
    cols_out[img * MT + rank] = (float)(pA - 1);
  }
  if (hasB && pB != 0){
    int rank = __popcll(mA) + __popcll(mB & lt);
    rows_out[img * MT + rank] = (float)(jB - 1);
    cols_out[img * MT + rank] = (float)(pB - 1);
  }
}

extern "C" void kernel_launch(void* const* d_in, const int* in_sizes, int n_in,
                              void* d_out, int out_size, void* d_ws, size_t ws_size,
                              hipStream_t stream) {
  const float* pm     = (const float*)d_in[0];
  const float* logits = (const float*)d_in[1];
  const float* tm     = (const float*)d_in[2];
  const int*   tids   = (const int*)d_in[3];

  float* C        = (float*)d_out;
  float* rows_out = C + CNT;
  float* cols_out = rows_out + NB * MT;

  // pick largest K-split that fits (Kc = HW/KS divisible by 64)
  static const int ks_opts[] = {80, 50, 40, 25, 10, 5, 2, 1};
  int KS = 1; size_t part_off = 0;
  for (int oi = 0; oi < 8; oi++){
    int o = ks_opts[oi];
    size_t norms = (size_t)o * (NPRED + NT) * 4 + (NPRED + NT) * 4;
    size_t po = (norms + 255) & ~(size_t)255;
    size_t need = po + (size_t)o * CNT * 4;
    if (need <= ws_size){ KS = o; part_off = po; break; }
  }
  char* ws = (char*)d_ws;
  float* pnp   = (float*)ws;
  float* tnp   = (float*)(ws + (size_t)KS * NPRED * 4);
  float* pnorm = (float*)(ws + (size_t)KS * (NPRED + NT) * 4);
  float* tnorm = pnorm + NPRED;
  float* part  = (float*)(ws + part_off);

  const int Kc = HW / KS;
  const int ksteps = Kc / 64;

  gemm_bf16<<<dim3(13, KS), 256, 0, stream>>>(pm, tm, part, pnp, tnp, Kc, ksteps);
  norm_reduce<<<4, 256, 0, stream>>>(pnp, tnp, pnorm, tnorm, KS);
  finalize<<<500, 256, 0, stream>>>(part, KS, pnorm, tnorm, logits, tids, C);
  hungarian<<<NB, 64, 0, stream>>>(C, rows_out, cols_out);
}

// Round 6
// 109.119 us; speedup vs baseline: 1.4666x; 1.1557x over previous
//
#include <hip/hip_runtime.h>
#include <math.h>

#define NB    8
#define NN    100
#define NPRED (NB*NN)     // 800
#define MT    20
#define NT    (NB*MT)     // 160
#define HW    25600
#define NCLS  80
#define CNT   (NPRED*NT)  // 128000
#define MTILES 13

typedef float  f32x4  __attribute__((ext_vector_type(4)));
typedef short  short8 __attribute__((ext_vector_type(8)));

static __device__ __forceinline__ unsigned short f2bf_rne(float f){
  unsigned u = __float_as_uint(f);
  return (unsigned short)((u + 0x7fffu + ((u >> 16) & 1u)) >> 16);
}

// async global->LDS, 16B per lane, no VGPR round trip
static __device__ __forceinline__ void gload16(const float* g, float* l){
  __builtin_amdgcn_global_load_lds((const __attribute__((address_space(1))) unsigned int*)g,
                                   (__attribute__((address_space(3))) unsigned int*)l, 16, 0, 0);
}

// ---------------- bf16 MFMA GEMM via global_load_lds (fp32 in LDS) ----------------
// Tile 64x160x64, 4 waves 2x2, wave tile 32x80 (2x5 frags of 16x16x32).
// LDS linear layout; XOR swizzle (16B granule ^ (row&7)) applied on the GLOBAL
// source address (DMA dest must stay linear) and re-applied on the LDS frag read.
// fp32 kept in LDS: norms accumulated exactly, bf16 convert at frag build.
__global__ __launch_bounds__(256, 2)
void gemm_dma(const float* __restrict__ A, const float* __restrict__ Bm,
              float* __restrict__ part, float* __restrict__ pnp,
              float* __restrict__ tnp, int Kc, int ksteps){
  __shared__ float sAB[14336];   // A: [0,4096) = 64x64, B: [4096,14336) = 160x64

  const int bid = blockIdx.x;
  const int mtile = bid % MTILES, ks = bid / MTILES;   // same-ks blocks adjacent
  const int t = threadIdx.x, lane = t & 63;
  const int w = t >> 6, wr = w >> 1, wc = w & 1;
  const int fr = lane & 15, fq = lane >> 4;
  const int kbase = ks * Kc;

  // staging source descriptors: 14 granules (16B) per thread, swizzled source
  const float* srcb[14];
  #pragma unroll
  for (int i = 0; i < 14; i++){
    const int s = i * 256 + t;
    int row, g;
    const float* base;
    if (s < 1024){
      row = s >> 4; g = s & 15;
      int gr = mtile * 64 + row; if (gr > NPRED - 1) gr = NPRED - 1;
      base = A + (size_t)gr * HW;
    } else {
      const int s2 = s - 1024;
      row = s2 >> 4; g = s2 & 15;
      base = Bm + (size_t)row * HW;
    }
    srcb[i] = base + ((g ^ (row & 7)) << 2);
  }

  f32x4 acc[2][5];
  #pragma unroll
  for (int r = 0; r < 2; r++)
    #pragma unroll
    for (int c = 0; c < 5; c++) acc[r][c] = (f32x4){0.f,0.f,0.f,0.f};

  float asum[2] = {0.f, 0.f};
  float bsum[5] = {0.f, 0.f, 0.f, 0.f, 0.f};

  for (int step = 0; step < ksteps; ++step){
    const int k0 = kbase + step * 64;
    #pragma unroll
    for (int i = 0; i < 14; i++)
      gload16(srcb[i] + k0, sAB + (i * 256 + t) * 4);
    __syncthreads();   // compiler drains vmcnt before barrier

    #pragma unroll
    for (int kk = 0; kk < 2; ++kk){
      const int g0 = ((kk * 4 + fq) * 2) ^ (fr & 7);
      short8 af[2];
      #pragma unroll
      for (int r = 0; r < 2; ++r){
        const int row = wr*32 + r*16 + fr;
        const f32x4 lo = *(const f32x4*)&sAB[row*64 + (g0 << 2)];
        const f32x4 hi = *(const f32x4*)&sAB[row*64 + ((g0 ^ 1) << 2)];
        if (wc == 0)
          asum[r] += lo[0]*lo[0]+lo[1]*lo[1]+lo[2]*lo[2]+lo[3]*lo[3]
                   + hi[0]*hi[0]+hi[1]*hi[1]+hi[2]*hi[2]+hi[3]*hi[3];
        short8 h;
        h[0]=(short)f2bf_rne(lo[0]); h[1]=(short)f2bf_rne(lo[1]);
        h[2]=(short)f2bf_rne(lo[2]); h[3]=(short)f2bf_rne(lo[3]);
        h[4]=(short)f2bf_rne(hi[0]); h[5]=(short)f2bf_rne(hi[1]);
        h[6]=(short)f2bf_rne(hi[2]); h[7]=(short)f2bf_rne(hi[3]);
        af[r] = h;
      }
      #pragma unroll
      for (int c = 0; c < 5; ++c){
        const int row = wc*80 + c*16 + fr;
        const f32x4 lo = *(const f32x4*)&sAB[4096 + row*64 + (g0 << 2)];
        const f32x4 hi = *(const f32x4*)&sAB[4096 + row*64 + ((g0 ^ 1) << 2)];
        if (wr == 0)
          bsum[c] += lo[0]*lo[0]+lo[1]*lo[1]+lo[2]*lo[2]+lo[3]*lo[3]
                   + hi[0]*hi[0]+hi[1]*hi[1]+hi[2]*hi[2]+hi[3]*hi[3];
        short8 b;
        b[0]=(short)f2bf_rne(lo[0]); b[1]=(short)f2bf_rne(lo[1]);
        b[2]=(short)f2bf_rne(lo[2]); b[3]=(short)f2bf_rne(lo[3]);
        b[4]=(short)f2bf_rne(hi[0]); b[5]=(short)f2bf_rne(hi[1]);
        b[6]=(short)f2bf_rne(hi[2]); b[7]=(short)f2bf_rne(hi[3]);
        acc[0][c] = __builtin_amdgcn_mfma_f32_16x16x32_bf16(af[0], b, acc[0][c], 0, 0, 0);
        acc[1][c] = __builtin_amdgcn_mfma_f32_16x16x32_bf16(af[1], b, acc[1][c], 0, 0, 0);
      }
    }
    __syncthreads();
  }

  // ---- norms: reduce over fq lanes (xor16 + xor32), gated waves write ----
  #pragma unroll
  for (int r = 0; r < 2; ++r){
    float s = asum[r];
    s += __shfl_xor(s, 16); s += __shfl_xor(s, 32);
    const int grow = mtile*64 + wr*32 + r*16 + fr;
    if (wc == 0 && fq == 0 && grow < NPRED) pnp[(size_t)ks * NPRED + grow] = s;
  }
  if (wr == 0 && mtile == 0){
    #pragma unroll
    for (int c = 0; c < 5; ++c){
      float s = bsum[c];
      s += __shfl_xor(s, 16); s += __shfl_xor(s, 32);
      if (fq == 0) tnp[(size_t)ks * NT + wc*80 + c*16 + fr] = s;
    }
  }

  // ---- store partials ----
  float* dst = part + (size_t)ks * CNT;
  #pragma unroll
  for (int r = 0; r < 2; r++)
    #pragma unroll
    for (int c = 0; c < 5; c++)
      #pragma unroll
      for (int i = 0; i < 4; i++){
        const int grow = mtile*64 + wr*32 + r*16 + fq*4 + i;
        if (grow < NPRED)
          dst[(size_t)grow * NT + wc*80 + c*16 + fr] = acc[r][c][i];
      }
}

// ---------------- reduce norm partials ----------------
__global__ __launch_bounds__(256) void norm_reduce(const float* __restrict__ pnp,
                                                   const float* __restrict__ tnp,
                                                   float* __restrict__ pn,
                                                   float* __restrict__ tn, int KS){
  int idx = blockIdx.x * 256 + threadIdx.x;
  if (idx < NPRED){
    float s = 0.f;
    for (int ks = 0; ks < KS; ks++) s += pnp[(size_t)ks * NPRED + idx];
    pn[idx] = s;
  } else if (idx < NPRED + NT){
    int j = idx - NPRED;
    float s = 0.f;
    for (int ks = 0; ks < KS; ks++) s += tnp[(size_t)ks * NT + j];
    tn[j] = s;
  }
}

// ---------------- finalize: reduce K-splits, dice + focal class cost ----------------
__global__ __launch_bounds__(256) void finalize(const float* __restrict__ part, int KS,
                                                const float* __restrict__ pnorm,
                                                const float* __restrict__ tnorm,
                                                const float* __restrict__ logits,
                                                const int* __restrict__ tgt_ids,
                                                float* __restrict__ C){
  int idx = blockIdx.x * 256 + threadIdx.x;
  int pred = idx / NT, tt = idx - pred * NT;
  const float* p = part + idx;
  double d0=0.0, d1=0.0, d2=0.0, d3=0.0;
  int ks = 0;
  for (; ks + 4 <= KS; ks += 4){
    d0 += (double)p[(size_t)(ks+0) * CNT];
    d1 += (double)p[(size_t)(ks+1) * CNT];
    d2 += (double)p[(size_t)(ks+2) * CNT];
    d3 += (double)p[(size_t)(ks+3) * CNT];
  }
  for (; ks < KS; ks++) d0 += (double)p[(size_t)ks * CNT];
  double dot = (d0 + d1) + (d2 + d3);
  double num = 2.0 * dot;
  double den = (double)pnorm[pred] + (double)tnorm[tt];
  double mask_score = -((num + 1e-4) / (den + 1e-4));
  double x = (double)logits[pred * NCLS + tgt_ids[tt]];
  double pl = 1.0 / (1.0 + exp(-x));
  double pos = 0.25 * (1.0 - pl) * (1.0 - pl) * (-log(pl + 1e-8));
  double neg = 0.75 * pl * pl * (-log(1.0 - pl + 1e-8));
  double cv = mask_score * 2.0 + (pos - neg);
  float o = (float)cv;
  if (!isfinite(o)) o = 0.0f;
  C[idx] = o;
}

// ---------------- Hungarian (JV), fp32 regs, DPP value-min + ballot argmin ----------------
static __device__ __forceinline__ float sel20(const float c[20], int k){
  const bool b0 = k & 1, b1 = k & 2;
  float t0 = b0 ? c[1]  : c[0],  t1 = b0 ? c[3]  : c[2];
  float t2 = b0 ? c[5]  : c[4],  t3 = b0 ? c[7]  : c[6];
  float t4 = b0 ? c[9]  : c[8],  t5 = b0 ? c[11] : c[10];
  float t6 = b0 ? c[13] : c[12], t7 = b0 ? c[15] : c[14];
  float t8 = b0 ? c[17] : c[16], t9 = b0 ? c[19] : c[18];
  float e0 = b1 ? t1 : t0, e1 = b1 ? t3 : t2, e2 = b1 ? t5 : t4;
  float e3 = b1 ? t7 : t6, e4 = b1 ? t9 : t8;
  const int hi = k >> 2;
  const bool h0 = hi & 1, h1 = hi & 2, h2 = hi & 4;
  float g0 = h0 ? e1 : e0, g1 = h0 ? e3 : e2;
  float m0 = h1 ? g1 : g0;
  return h2 ? e4 : m0;
}

static __device__ __forceinline__ float dppmin(float v, int ctrl_unused, int ctrl){
  (void)ctrl_unused;
  int x;
  switch (ctrl){
    case 0xB1:  x = __builtin_amdgcn_update_dpp(0, __float_as_int(v), 0xB1,  0xF, 0xF, true); break;
    case 0x4E:  x = __builtin_amdgcn_update_dpp(0, __float_as_int(v), 0x4E,  0xF, 0xF, true); break;
    case 0x124: x = __builtin_amdgcn_update_dpp(0, __float_as_int(v), 0x124, 0xF, 0xF, true); break;
    default:    x = __builtin_amdgcn_update_dpp(0, __float_as_int(v), 0x128, 0xF, 0xF, true); break;
  }
  return fminf(v, __int_as_float(x));
}

__global__ __launch_bounds__(64) void hungarian(const float* __restrict__ C,
                                                float* __restrict__ rows_out,
                                                float* __restrict__ cols_out){
  const int img  = blockIdx.x;
  const int lane = threadIdx.x;
  const int jA = lane + 1, jB = lane + 65;
  const bool hasB = (jB <= NN);

  float ca[20], cb[20];
  {
    const float* basep = C + (size_t)img * NN * NT + (size_t)lane * NT + img * MT;
    #pragma unroll
    for (int r = 0; r < 5; r++){
      float4 x = *(const float4*)(basep + r*4);
      ca[r*4+0]=x.x; ca[r*4+1]=x.y; ca[r*4+2]=x.z; ca[r*4+3]=x.w;
    }
    if (hasB){
      const float* basep2 = basep + (size_t)64 * NT;
      #pragma unroll
      for (int r = 0; r < 5; r++){
        float4 x = *(const float4*)(basep2 + r*4);
        cb[r*4+0]=x.x; cb[r*4+1]=x.y; cb[r*4+2]=x.z; cb[r*4+3]=x.w;
      }
    } else {
      #pragma unroll
      for (int r = 0; r < 20; r++) cb[r] = 0.f;
    }
  }

  const float INF = 1e30f;
  float vA = 0.f, vB = 0.f, u_reg = 0.f;
  int pA = 0, pB = 0;

  for (int i = 1; i <= MT; i++){
    float minA = INF, minB = INF;
    int wayA = 0, wayB = 0;
    bool usedA = false, usedB = false, inTree = false;
    int j0 = 0, i0 = i;

    while (true){
      if (j0 != 0){
        if (j0 <= 64){ if (lane == j0 - 1)  usedA = true; }
        else         { if (lane == j0 - 65) usedB = true; }
      }
      if (lane == i0 - 1) inTree = true;
      float ui0 = __shfl(u_reg, i0 - 1);
      // relax free columns
      if (!usedA){
        float cur = sel20(ca, i0 - 1) - ui0 - vA;
        if (cur < minA){ minA = cur; wayA = j0; }
      }
      if (hasB && !usedB){
        float cur = sel20(cb, i0 - 1) - ui0 - vB;
        if (cur < minB){ minB = cur; wayB = j0; }
      }
      // value-only min reduce (exact), then index via ballot (np.argmin tie-break)
      float candA = usedA ? INF : minA;
      float candB = (hasB && !usedB) ? minB : INF;
      float v = fminf(candA, candB);
      v = dppmin(v, 0, 0xB1);   // quad xor1
      v = dppmin(v, 0, 0x4E);   // quad xor2
      v = dppmin(v, 0, 0x124);  // row_ror:4
      v = dppmin(v, 0, 0x128);  // row_ror:8
      v = fminf(v, __shfl_xor(v, 16));
      v = fminf(v, __shfl_xor(v, 32));
      const float delta = v;
      unsigned long long mAm = __ballot(candA == delta);
      unsigned long long mBm = __ballot(candB == delta);
      const int j1 = mAm ? __ffsll(mAm) : 64 + __ffsll(mBm);
      // dual updates
      if (lane < MT && inTree) u_reg += delta;
      if (usedA) vA -= delta; else minA -= delta;
      if (hasB){ if (usedB) vB -= delta; else minB -= delta; }
      j0 = j1;
      int pa = __shfl(pA, (j0 - 1) & 63);
      int pb = __shfl(pB, (j0 - 65) & 63);
      int pj = (j0 <= 64) ? pa : pb;
      if (pj == 0) break;
      i0 = pj;   // cached lookup doubles as next pass's row
    }
    // augmenting path flip
    int j = j0;
    while (true){
      int wjA = __shfl(wayA, (j - 1) & 63);
      int wjB = __shfl(wayB, (j - 65) & 63);
      int wj = (j <= 64) ? wjA : wjB;
      int pv;
      if (wj == 0) pv = i;
      else {
        int pa = __shfl(pA, (wj - 1) & 63);
        int pb = __shfl(pB, (wj - 65) & 63);
        pv = (wj <= 64) ? pa : pb;
      }
      if (j <= 64){ if (lane == j - 1)  pA = pv; }
      else        { if (lane == j - 65) pB = pv; }
      j = wj;
      if (j == 0) break;
    }
  }

  unsigned long long mA = __ballot(pA != 0);
  unsigned long long mB = __ballot(hasB && pB != 0);
  unsigned long long lt = (1ull << lane) - 1ull;
  if (pA != 0){
    int rank = __popcll(mA & lt);
    rows_out[img * MT + rank] = (float)(jA - 1);
    cols_out[img * MT + rank] = (float)(pA - 1);
  }
  if (hasB && pB != 0){
    int rank = __popcll(mA) + __popcll(mB & lt);
    rows_out[img * MT + rank] = (float)(jB - 1);
    cols_out[img * MT + rank] = (float)(pB - 1);
  }
}

extern "C" void kernel_launch(void* const* d_in, const int* in_sizes, int n_in,
                              void* d_out, int out_size, void* d_ws, size_t ws_size,
                              hipStream_t stream) {
  const float* pm     = (const float*)d_in[0];
  const float* logits = (const float*)d_in[1];
  const float* tm     = (const float*)d_in[2];
  const int*   tids   = (const int*)d_in[3];

  float* C        = (float*)d_out;
  float* rows_out = C + CNT;
  float* cols_out = rows_out + NB * MT;

  // largest K-split fitting workspace; Kc divisible by 64
  static const int ks_opts[] = {40, 25, 10, 5, 2, 1};
  int KS = 1; size_t part_off = 0;
  for (int oi = 0; oi < 6; oi++){
    int o = ks_opts[oi];
    size_t norms = (size_t)o * (NPRED + NT) * 4 + (NPRED + NT) * 4;
    size_t po = (norms + 255) & ~(size_t)255;
    size_t need = po + (size_t)o * CNT * 4;
    if (need <= ws_size){ KS = o; part_off = po; break; }
  }
  char* ws = (char*)d_ws;
  float* pnp   = (float*)ws;
  float* tnp   = (float*)(ws + (size_t)KS * NPRED * 4);
  float* pnorm = (float*)(ws + (size_t)KS * (NPRED + NT) * 4);
  float* tnorm = pnorm + NPRED;
  float* part  = (float*)(ws + part_off);

  const int Kc = HW / KS;
  const int ksteps = Kc / 64;

  gemm_dma<<<MTILES * KS, 256, 0, stream>>>(pm, tm, part, pnp, tnp, Kc, ksteps);
  norm_reduce<<<4, 256, 0, stream>>>(pnp, tnp, pnorm, tnorm, KS);
  finalize<<<500, 256, 0, stream>>>(part, KS, pnorm, tnorm, logits, tids, C);
  hungarian<<<NB, 64, 0, stream>>>(C, rows_out, cols_out);
}